// Round 1
// baseline (360.765 us; speedup 1.0000x reference)
//
#include <hip/hip_runtime.h>

#define B_ 4
#define L_ 1024
#define DIM_ 1024
#define H_ 8
#define D_ 32
#define LSEG 64
#define NSEG (L_/LSEG)   // 16

typedef __bf16 bf16_t;
typedef __bf16 bf16x8 __attribute__((ext_vector_type(8)));
typedef float f32x4 __attribute__((ext_vector_type(4)));

// ---------------- f32 -> bf16 bulk convert (4 elems/thread) ----------------
__global__ __launch_bounds__(256) void cvt_bf16(const float* __restrict__ in,
                                                bf16_t* __restrict__ out, int n4) {
  int i = blockIdx.x * 256 + threadIdx.x;
  if (i < n4) {
    float4 v = ((const float4*)in)[i];
    union { bf16_t b[4]; unsigned long long q; } pk;
    pk.b[0] = (bf16_t)v.x; pk.b[1] = (bf16_t)v.y;
    pk.b[2] = (bf16_t)v.z; pk.b[3] = (bf16_t)v.w;
    ((unsigned long long*)out)[i] = pk.q;
  }
}

// ---------------- NT GEMM: C[m][n] = act(sum_k A[m][k]*B[n][k] + bias[n]) ----
// A: [M,K] bf16 row-major, B: [N,K] bf16 row-major. M%64==0, N%64==0, K%64==0.
// ACT: 0=none, 1=silu.  OUTBF: 1 -> bf16 out, 0 -> f32 out.
template<int ACT, int OUTBF>
__global__ __launch_bounds__(256) void gemm_nt(const bf16_t* __restrict__ A,
                                               const bf16_t* __restrict__ Bm,
                                               const float* __restrict__ bias,
                                               void* __restrict__ Cout,
                                               int M, int N, int K) {
  __shared__ __align__(16) bf16_t As[64][72];
  __shared__ __align__(16) bf16_t Bs[64][72];
  const int t = threadIdx.x;
  const int bm = blockIdx.x, bn = blockIdx.y;
  const int row = t >> 2;           // 0..63
  const int kc  = (t & 3) * 16;     // 0,16,32,48
  const int wid = t >> 6, lane = t & 63;
  const int wr = wid >> 1, wc = wid & 1;   // 2x2 waves
  const int lr = lane & 15, lq = lane >> 4;
  f32x4 acc[2][2] = {};
  const bf16_t* Ag = A  + (size_t)(bm*64 + row) * K + kc;
  const bf16_t* Bg = Bm + (size_t)(bn*64 + row) * K + kc;
  for (int k0 = 0; k0 < K; k0 += 64) {
    *(uint4*)&As[row][kc]   = *(const uint4*)(Ag);
    *(uint4*)&As[row][kc+8] = *(const uint4*)(Ag + 8);
    *(uint4*)&Bs[row][kc]   = *(const uint4*)(Bg);
    *(uint4*)&Bs[row][kc+8] = *(const uint4*)(Bg + 8);
    Ag += 64; Bg += 64;
    __syncthreads();
#pragma unroll
    for (int ks = 0; ks < 2; ++ks) {
      bf16x8 af0 = *(const bf16x8*)&As[wr*32      + lr][ks*32 + lq*8];
      bf16x8 af1 = *(const bf16x8*)&As[wr*32 + 16 + lr][ks*32 + lq*8];
      bf16x8 bf0 = *(const bf16x8*)&Bs[wc*32      + lr][ks*32 + lq*8];
      bf16x8 bf1 = *(const bf16x8*)&Bs[wc*32 + 16 + lr][ks*32 + lq*8];
      acc[0][0] = __builtin_amdgcn_mfma_f32_16x16x32_bf16(af0, bf0, acc[0][0], 0, 0, 0);
      acc[0][1] = __builtin_amdgcn_mfma_f32_16x16x32_bf16(af0, bf1, acc[0][1], 0, 0, 0);
      acc[1][0] = __builtin_amdgcn_mfma_f32_16x16x32_bf16(af1, bf0, acc[1][0], 0, 0, 0);
      acc[1][1] = __builtin_amdgcn_mfma_f32_16x16x32_bf16(af1, bf1, acc[1][1], 0, 0, 0);
    }
    __syncthreads();
  }
#pragma unroll
  for (int mi = 0; mi < 2; ++mi) {
#pragma unroll
    for (int ni = 0; ni < 2; ++ni) {
      int colg = bn*64 + wc*32 + ni*16 + lr;
      float bb = bias[colg];
#pragma unroll
      for (int r = 0; r < 4; ++r) {
        int rowg = bm*64 + wr*32 + mi*16 + lq*4 + r;
        float v = acc[mi][ni][r] + bb;
        if (ACT == 1) v = v / (1.0f + __expf(-v));
        if (OUTBF) ((bf16_t*)Cout)[(size_t)rowg * N + colg] = (bf16_t)v;
        else       ((float*)Cout)[(size_t)rowg * N + colg] = v;
      }
    }
  }
}

// ---------------- Pass 1: segmented scan --------------------------------
// qkva layout per (b,l,h): [D][4 comps][2 reim] floats. comp: 0=q,1=k,2=v,3=a.
// Thread map: wave w (0..3), lane: e = w*8 + (lane>>3); dg = lane&7; d = dg*4+j.
__global__ __launch_bounds__(256) void scan_seg(const float* __restrict__ qkva,
                                                float* __restrict__ y_loc,
                                                float* __restrict__ qP,
                                                float* __restrict__ Aseg,
                                                float* __restrict__ Hfin) {
  const int wg = blockIdx.x;
  const int s  = wg & (NSEG - 1);
  const int bh = wg >> 4;          // NSEG==16
  const int h  = bh & (H_ - 1);
  const int b  = bh >> 3;          // H_==8
  const int t = threadIdx.x;
  const int w = t >> 6, lane = t & 63;
  const int el = lane >> 3;
  const int e  = w * 8 + el;
  const int dg = lane & 7;
  const bool sq = (w == 0) && (el == 0);   // lanes 0..7 of wave 0 store per-d data
  float hr[4] = {0,0,0,0}, hi[4] = {0,0,0,0};
  float Pr[4] = {1,1,1,1}, Pi[4] = {0,0,0,0};
  for (int l = 0; l < LSEG; ++l) {
    const int lg = s * LSEG + l;
    const float* base = qkva + ((size_t)(b*L_ + lg)*H_ + h) * (D_*8);
    float vr = base[e*8 + 4], vi = base[e*8 + 5];
    float ypr = 0.f, ypi = 0.f;
    float qpb[8];
#pragma unroll
    for (int j = 0; j < 4; ++j) {
      const float* pd = base + (dg*4 + j) * 8;
      float qr = pd[0], qi = pd[1];
      float kr = pd[2], ki = pd[3];
      float ar = pd[6], ai = pd[7];
      float m2 = ar*ar + ai*ai;
      // rsqrt(m2)*sigmoid(log(m2)) == sqrt(m2)/(1+m2)
      float sc = sqrtf(m2) / (1.0f + m2);
      ar *= sc; ai *= sc;
      float kvr = kr*vr - ki*vi;
      float kvi = kr*vi + ki*vr;
      float nhr = ar*hr[j] - ai*hi[j] + kvr;
      float nhi = ar*hi[j] + ai*hr[j] + kvi;
      hr[j] = nhr; hi[j] = nhi;
      ypr += qr*nhr - qi*nhi;
      ypi += qr*nhi + qi*nhr;
      float nPr = ar*Pr[j] - ai*Pi[j];
      float nPi = ar*Pi[j] + ai*Pr[j];
      Pr[j] = nPr; Pi[j] = nPi;
      qpb[j*2+0] = qr*nPr - qi*nPi;
      qpb[j*2+1] = qr*nPi + qi*nPr;
    }
    if (sq) {
      float* qpo = qP + (((size_t)(b*L_ + lg)*H_ + h)*D_ + dg*4) * 2;
#pragma unroll
      for (int j2 = 0; j2 < 8; ++j2) qpo[j2] = qpb[j2];
    }
    // reduce y over dg (8 consecutive lanes share e)
    ypr += __shfl_down(ypr, 4); ypi += __shfl_down(ypi, 4);
    ypr += __shfl_down(ypr, 2); ypi += __shfl_down(ypi, 2);
    ypr += __shfl_down(ypr, 1); ypi += __shfl_down(ypi, 1);
    if (dg == 0) {
      float* yo = y_loc + (((size_t)(b*L_ + lg)*H_ + h)*D_ + e) * 2;
      yo[0] = ypr; yo[1] = ypi;
    }
  }
  const size_t segb = ((size_t)bh * NSEG + s) * D_;
  if (sq) {
    float* ao = Aseg + (segb + dg*4) * 2;
#pragma unroll
    for (int j = 0; j < 4; ++j) { ao[j*2] = Pr[j]; ao[j*2+1] = Pi[j]; }
  }
#pragma unroll
  for (int j = 0; j < 4; ++j) {
    float* ho = Hfin + ((segb + dg*4 + j) * D_ + e) * 2;
    ho[0] = hr[j]; ho[1] = hi[j];
  }
}

// ---------------- Pass 2: combine segments, emit carry-in per segment -----
__global__ __launch_bounds__(256) void seg_combine(const float* __restrict__ h0re,
                                                   const float* __restrict__ h0im,
                                                   const float* __restrict__ Aseg,
                                                   const float* __restrict__ Hfin,
                                                   float* __restrict__ Hc) {
  const int bh = blockIdx.x;
  const int h = bh & (H_ - 1);
  const int t = threadIdx.x;
  const int w = t >> 6, lane = t & 63;
  const int e = w * 8 + (lane >> 3);
  const int dg = lane & 7;
  float cr[4], ci[4];
#pragma unroll
  for (int j = 0; j < 4; ++j) {
    int d = dg*4 + j;
    cr[j] = h0re[((size_t)h*D_ + d)*D_ + e];
    ci[j] = h0im[((size_t)h*D_ + d)*D_ + e];
  }
  for (int s = 0; s < NSEG; ++s) {
    const size_t segb = ((size_t)bh * NSEG + s) * D_;
#pragma unroll
    for (int j = 0; j < 4; ++j) {
      int d = dg*4 + j;
      float* o = Hc + ((segb + d)*D_ + e)*2;
      o[0] = cr[j]; o[1] = ci[j];
      float ar = Aseg[(segb + d)*2], ai = Aseg[(segb + d)*2 + 1];
      const float* fp = Hfin + ((segb + d)*D_ + e)*2;
      float nr = ar*cr[j] - ai*ci[j] + fp[0];
      float ni = ar*ci[j] + ai*cr[j] + fp[1];
      cr[j] = nr; ci[j] = ni;
    }
  }
}

// ---------------- Pass 3: y += qP @ Hcarry; emit y2 (bf16) ----------------
__global__ __launch_bounds__(256) void y_correct(const float* __restrict__ y_loc,
                                                 const float* __restrict__ qP,
                                                 const float* __restrict__ Hc,
                                                 bf16_t* __restrict__ y2b) {
  __shared__ __align__(16) float Hs[D_ * D_ * 2];
  const int wg = blockIdx.x;
  const int s  = wg & (NSEG - 1);
  const int bh = wg >> 4;
  const int h  = bh & (H_ - 1);
  const int b  = bh >> 3;
  const int t = threadIdx.x;
  const float4* src = (const float4*)(Hc + (size_t)wg * (D_*D_*2));
  float4* dst = (float4*)Hs;
  dst[t] = src[t];
  dst[t + 256] = src[t + 256];
  __syncthreads();
  const int l  = t >> 2;
  const int eb = (t & 3) * 8;
  const int lg = s * LSEG + l;
  const size_t rowc = ((size_t)(b*L_ + lg)*H_ + h) * D_;
  const float* qpr = qP + rowc * 2;
  float ac_r[8], ac_i[8];
#pragma unroll
  for (int je = 0; je < 8; ++je) {
    ac_r[je] = y_loc[(rowc + eb + je)*2];
    ac_i[je] = y_loc[(rowc + eb + je)*2 + 1];
  }
  for (int d = 0; d < D_; ++d) {
    float pr = qpr[d*2], pi = qpr[d*2 + 1];
#pragma unroll
    for (int je = 0; je < 8; ++je) {
      float hrv = Hs[(d*D_ + eb + je)*2], hiv = Hs[(d*D_ + eb + je)*2 + 1];
      ac_r[je] += pr*hrv - pi*hiv;
      ac_i[je] += pr*hiv + pi*hrv;
    }
  }
  bf16_t* yo = y2b + (size_t)(b*L_ + lg) * (H_*D_*2) + (h*D_ + eb)*2;
#pragma unroll
  for (int je = 0; je < 8; ++je) {
    yo[je*2]     = (bf16_t)ac_r[je];
    yo[je*2 + 1] = (bf16_t)ac_i[je];
  }
}

// ---------------- launcher ------------------------------------------------
extern "C" void kernel_launch(void* const* d_in, const int* in_sizes, int n_in,
                              void* d_out, int out_size, void* d_ws, size_t ws_size,
                              hipStream_t stream) {
  const float* x      = (const float*)d_in[0];
  const float* W_in   = (const float*)d_in[1];
  const float* b_in   = (const float*)d_in[2];
  const float* W_qkva = (const float*)d_in[3];
  const float* b_qkva = (const float*)d_in[4];
  const float* W_y    = (const float*)d_in[5];
  const float* b_y    = (const float*)d_in[6];
  const float* W_out  = (const float*)d_in[7];
  const float* b_out  = (const float*)d_in[8];
  const float* h0re   = (const float*)d_in[9];
  const float* h0im   = (const float*)d_in[10];

  char* w = (char*)d_ws;
  const size_t MB = 1ull << 20;
  // lifetimes: xb dead after GEMM1 -> qP; u dead after GEMM2 -> y_loc;
  // qkva dead after scan -> {Hc, y2, z}
  bf16_t* Wb_in   = (bf16_t*)(w + 0*MB);    // 2 MB
  bf16_t* Wb_qkva = (bf16_t*)(w + 2*MB);    // 4 MB
  bf16_t* Wb_y    = (bf16_t*)(w + 6*MB);    // 1 MB
  bf16_t* Wb_out  = (bf16_t*)(w + 7*MB);    // 2 MB
  bf16_t* xb      = (bf16_t*)(w + 9*MB);    // 8 MB
  float*  qP      = (float*) (w + 9*MB);    // 8 MB (overlay xb)
  bf16_t* u       = (bf16_t*)(w + 17*MB);   // 8 MB
  float*  y_loc   = (float*) (w + 17*MB);   // 8 MB (overlay u)
  float*  qkva    = (float*) (w + 25*MB);   // 32 MB
  float*  Hc      = (float*) (w + 25*MB);   // 16 MB (overlay qkva)
  bf16_t* y2b     = (bf16_t*)(w + 41*MB);   // 4 MB  (overlay qkva)
  bf16_t* z       = (bf16_t*)(w + 45*MB);   // 8 MB  (overlay qkva)
  float*  Aseg    = (float*) (w + 57*MB);   // 0.125 MB
  float*  Hfin    = (float*) (w + 58*MB);   // 16 MB -> total 74 MB

  // convert inputs/weights to bf16
  cvt_bf16<<<4096, 256, 0, stream>>>(x,      xb,      1048576);
  cvt_bf16<<<1024, 256, 0, stream>>>(W_in,   Wb_in,   262144);
  cvt_bf16<<<2048, 256, 0, stream>>>(W_qkva, Wb_qkva, 524288);
  cvt_bf16<<<512,  256, 0, stream>>>(W_y,    Wb_y,    131072);
  cvt_bf16<<<1024, 256, 0, stream>>>(W_out,  Wb_out,  262144);

  // u = silu(x @ W_in^T + b_in)
  gemm_nt<1,1><<<dim3(64,16), 256, 0, stream>>>(xb, Wb_in, b_in, u, 4096, 1024, 1024);
  // qkva = u @ W_qkva^T + b_qkva  (f32 out)
  gemm_nt<0,0><<<dim3(64,32), 256, 0, stream>>>(u, Wb_qkva, b_qkva, qkva, 4096, 2048, 1024);
  // recurrence
  scan_seg  <<<B_*H_*NSEG, 256, 0, stream>>>(qkva, y_loc, qP, Aseg, Hfin);
  seg_combine<<<B_*H_,     256, 0, stream>>>(h0re, h0im, Aseg, Hfin, Hc);
  y_correct <<<B_*H_*NSEG, 256, 0, stream>>>(y_loc, qP, Hc, y2b);
  // z = silu(y2 @ W_y^T + b_y)
  gemm_nt<1,1><<<dim3(64,16), 256, 0, stream>>>(y2b, Wb_y, b_y, z, 4096, 1024, 512);
  // out = z @ W_out^T + b_out  (f32)
  gemm_nt<0,0><<<dim3(64,16), 256, 0, stream>>>(z, Wb_out, b_out, (float*)d_out, 4096, 1024, 1024);
}

// Round 2
// 343.226 us; speedup vs baseline: 1.0511x; 1.0511x over previous
//
#include <hip/hip_runtime.h>

#define B_ 4
#define L_ 1024
#define DIM_ 1024
#define H_ 8
#define D_ 32
#define LSEG 32
#define NSEG (L_/LSEG)   // 32

typedef __bf16 bf16_t;
typedef __bf16 bf16x8 __attribute__((ext_vector_type(8)));
typedef float f32x4 __attribute__((ext_vector_type(4)));

__device__ __forceinline__ void gload_lds16(const bf16_t* g, bf16_t* l) {
  __builtin_amdgcn_global_load_lds((const __attribute__((address_space(1))) void*)g,
                                   (__attribute__((address_space(3))) void*)l, 16, 0, 0);
}

// ---------------- f32 -> bf16 bulk convert (4 elems/thread) ----------------
__global__ __launch_bounds__(256) void cvt_bf16(const float* __restrict__ in,
                                                bf16_t* __restrict__ out, int n4) {
  int i = blockIdx.x * 256 + threadIdx.x;
  if (i < n4) {
    float4 v = ((const float4*)in)[i];
    union { bf16_t b[4]; unsigned long long q; } pk;
    pk.b[0] = (bf16_t)v.x; pk.b[1] = (bf16_t)v.y;
    pk.b[2] = (bf16_t)v.z; pk.b[3] = (bf16_t)v.w;
    ((unsigned long long*)out)[i] = pk.q;
  }
}

// ---------------- NT GEMM, m97-style ---------------------------------------
// C[m][n] = act(sum_k A[m][k]*B[n][k] + bias[n])
// A: [M,K] bf16 rm, B: [N,K] bf16 rm. BN=128, BK=64. BM in {64,128}.
// 256 thr = 4 waves in 2x2; wave tile (BM/2)x64; MI=BM/32 x 4 mfma tiles.
// Staging via global_load_lds width=16 into unpadded [rows][64] LDS.
template<int BM, int ACT, int OUTBF>
__global__ __launch_bounds__(256) void gemm_nt(const bf16_t* __restrict__ A,
                                               const bf16_t* __restrict__ Bm,
                                               const float* __restrict__ bias,
                                               void* __restrict__ Cout,
                                               int M, int N, int K) {
  constexpr int MI = BM / 32;
  constexpr int ISS_A = BM / 32;      // issues of 8 rows per wave for A
  __shared__ __align__(16) bf16_t As[BM * 64];
  __shared__ __align__(16) bf16_t Bs[128 * 64];
  const int t = threadIdx.x;
  const int wid = t >> 6, lane = t & 63;
  const int wr = wid >> 1, wc = wid & 1;
  const int lr = lane & 15, lq = lane >> 4;
  const int bm = blockIdx.x, bn = blockIdx.y;
  // staging coords: lane covers 16B: row = base + lane/8, col16 = lane%8
  const int rA = wid * (BM / 4) + (lane >> 3);
  const int rB = wid * 32 + (lane >> 3);
  const int c8 = (lane & 7) * 8;   // bf16 col
  const bf16_t* Ag = A + (size_t)(bm * BM + rA) * K + c8;
  const bf16_t* Bg = Bm + (size_t)(bn * 128 + rB) * K + c8;
  bf16_t* AsW = As + (wid * (BM / 4)) * 64;   // wave-uniform LDS bases
  bf16_t* BsW = Bs + (wid * 32) * 64;
  f32x4 acc[MI][4] = {};
  for (int k0 = 0; k0 < K; k0 += 64) {
#pragma unroll
    for (int j = 0; j < ISS_A; ++j)
      gload_lds16(Ag + (size_t)j * 8 * K, AsW + j * 8 * 64);
#pragma unroll
    for (int j = 0; j < 4; ++j)
      gload_lds16(Bg + (size_t)j * 8 * K, BsW + j * 8 * 64);
    Ag += 64; Bg += 64;
    __syncthreads();
#pragma unroll
    for (int ks = 0; ks < 2; ++ks) {
      bf16x8 af[MI], bfv[4];
#pragma unroll
      for (int mi = 0; mi < MI; ++mi)
        af[mi] = *(const bf16x8*)&As[(wr * (BM/2) + mi * 16 + lr) * 64 + ks * 32 + lq * 8];
#pragma unroll
      for (int ni = 0; ni < 4; ++ni)
        bfv[ni] = *(const bf16x8*)&Bs[(wc * 64 + ni * 16 + lr) * 64 + ks * 32 + lq * 8];
#pragma unroll
      for (int mi = 0; mi < MI; ++mi)
#pragma unroll
        for (int ni = 0; ni < 4; ++ni)
          acc[mi][ni] = __builtin_amdgcn_mfma_f32_16x16x32_bf16(af[mi], bfv[ni], acc[mi][ni], 0, 0, 0);
    }
    __syncthreads();
  }
#pragma unroll
  for (int mi = 0; mi < MI; ++mi) {
#pragma unroll
    for (int ni = 0; ni < 4; ++ni) {
      int colg = bn * 128 + wc * 64 + ni * 16 + lr;
      float bb = bias[colg];
#pragma unroll
      for (int r = 0; r < 4; ++r) {
        int rowg = bm * BM + wr * (BM/2) + mi * 16 + lq * 4 + r;
        float v = acc[mi][ni][r] + bb;
        if (ACT == 1) v = v / (1.0f + __expf(-v));
        if (OUTBF) ((bf16_t*)Cout)[(size_t)rowg * N + colg] = (bf16_t)v;
        else       ((float*)Cout)[(size_t)rowg * N + colg] = v;
      }
    }
  }
}

// ---------------- Pass 1: segmented scan (vectorized + prefetch) -----------
// qkva per (b,l,h): [D][q_r,q_i,k_r,k_i,v_r,v_i,a_r,a_i]. Thread: e = w*8+(lane>>3),
// dg = lane&7 covers d = dg*4+j (j<4). Lanes 0..7 (sq) store per-d outputs.
__global__ __launch_bounds__(256) void scan_seg(const float* __restrict__ qkva,
                                                float* __restrict__ y_loc,
                                                float* __restrict__ qP,
                                                float* __restrict__ Aseg,
                                                float* __restrict__ Hfin) {
  const int wg = blockIdx.x;
  const int s  = wg & (NSEG - 1);
  const int bh = wg >> 5;            // NSEG==32
  const int h  = bh & (H_ - 1);
  const int b  = bh >> 3;
  const int t = threadIdx.x;
  const int lane = t & 63;
  const int e  = (t >> 6) * 8 + (lane >> 3);
  const int dg = lane & 7;
  const bool sq = (t < 8);
  float hr[4] = {0,0,0,0}, hi[4] = {0,0,0,0};
  float Pr[4] = {1,1,1,1}, Pi[4] = {0,0,0,0};
  const float* base0 = qkva + ((size_t)(b*L_ + s*LSEG)*H_ + h) * (D_*8);
  const int STRIDE = H_ * D_ * 8;  // 2048 floats per step

  float4 qkA[4], vaA[4]; float2 vvA;
  float4 qkB[4], vaB[4]; float2 vvB;

#define LOADSTEP(l, qk, va, vv) { \
    const float* bp = base0 + (size_t)(l) * STRIDE; \
    vv = *(const float2*)(bp + e*8 + 4); \
    _Pragma("unroll") for (int j = 0; j < 4; ++j) { \
      qk[j] = *(const float4*)(bp + (dg*4 + j)*8); \
      va[j] = *(const float4*)(bp + (dg*4 + j)*8 + 4); } }

#define STEP(l, qk, va, vv) { \
    float ypr = 0.f, ypi = 0.f; float qpb[8]; \
    _Pragma("unroll") for (int j = 0; j < 4; ++j) { \
      float qr = qk[j].x, qi = qk[j].y, kr = qk[j].z, ki = qk[j].w; \
      float ar = va[j].z, ai = va[j].w; \
      float m2 = ar*ar + ai*ai; \
      float sc = sqrtf(m2) / (1.0f + m2); \
      ar *= sc; ai *= sc; \
      float kvr = kr*vv.x - ki*vv.y, kvi = kr*vv.y + ki*vv.x; \
      float nhr = ar*hr[j] - ai*hi[j] + kvr; \
      float nhi = ar*hi[j] + ai*hr[j] + kvi; \
      hr[j] = nhr; hi[j] = nhi; \
      ypr += qr*nhr - qi*nhi; ypi += qr*nhi + qi*nhr; \
      float nPr = ar*Pr[j] - ai*Pi[j], nPi = ar*Pi[j] + ai*Pr[j]; \
      Pr[j] = nPr; Pi[j] = nPi; \
      qpb[2*j]   = qr*nPr - qi*nPi; \
      qpb[2*j+1] = qr*nPi + qi*nPr; } \
    ypr += __shfl_down(ypr, 4); ypi += __shfl_down(ypi, 4); \
    ypr += __shfl_down(ypr, 2); ypi += __shfl_down(ypi, 2); \
    ypr += __shfl_down(ypr, 1); ypi += __shfl_down(ypi, 1); \
    const size_t rowc = ((size_t)(b*L_ + s*LSEG + (l))*H_ + h) * D_; \
    if (sq) { \
      float4* qpo = (float4*)(qP + (rowc + dg*4)*2); \
      qpo[0] = make_float4(qpb[0], qpb[1], qpb[2], qpb[3]); \
      qpo[1] = make_float4(qpb[4], qpb[5], qpb[6], qpb[7]); } \
    if (dg == 0) { \
      *(float2*)(y_loc + (rowc + e)*2) = make_float2(ypr, ypi); } }

  LOADSTEP(0, qkA, vaA, vvA);
  for (int l = 0; l < LSEG; l += 2) {
    LOADSTEP(l+1, qkB, vaB, vvB);
    STEP(l, qkA, vaA, vvA);
    if (l + 2 < LSEG) LOADSTEP(l+2, qkA, vaA, vvA);
    STEP(l+1, qkB, vaB, vvB);
  }
#undef LOADSTEP
#undef STEP
  const size_t segb = ((size_t)bh * NSEG + s) * D_;
  if (sq) {
    float* ao = Aseg + (segb + dg*4) * 2;
#pragma unroll
    for (int j = 0; j < 4; ++j) { ao[j*2] = Pr[j]; ao[j*2+1] = Pi[j]; }
  }
#pragma unroll
  for (int j = 0; j < 4; ++j) {
    float* ho = Hfin + ((segb + dg*4 + j) * D_ + e) * 2;
    ho[0] = hr[j]; ho[1] = hi[j];
  }
}

// ---------------- Pass 2: combine segments, emit carry-in per segment -----
__global__ __launch_bounds__(256) void seg_combine(const float* __restrict__ h0re,
                                                   const float* __restrict__ h0im,
                                                   const float* __restrict__ Aseg,
                                                   const float* __restrict__ Hfin,
                                                   float* __restrict__ Hc) {
  const int bh = blockIdx.x;
  const int h = bh & (H_ - 1);
  const int t = threadIdx.x;
  const int lane = t & 63;
  const int e = (t >> 6) * 8 + (lane >> 3);
  const int dg = lane & 7;
  float cr[4], ci[4];
#pragma unroll
  for (int j = 0; j < 4; ++j) {
    int d = dg*4 + j;
    cr[j] = h0re[((size_t)h*D_ + d)*D_ + e];
    ci[j] = h0im[((size_t)h*D_ + d)*D_ + e];
  }
  for (int s = 0; s < NSEG; ++s) {
    const size_t segb = ((size_t)bh * NSEG + s) * D_;
#pragma unroll
    for (int j = 0; j < 4; ++j) {
      int d = dg*4 + j;
      float* o = Hc + ((segb + d)*D_ + e)*2;
      o[0] = cr[j]; o[1] = ci[j];
      float ar = Aseg[(segb + d)*2], ai = Aseg[(segb + d)*2 + 1];
      const float* fp = Hfin + ((segb + d)*D_ + e)*2;
      float nr = ar*cr[j] - ai*ci[j] + fp[0];
      float ni = ar*ci[j] + ai*cr[j] + fp[1];
      cr[j] = nr; ci[j] = ni;
    }
  }
}

// ---------------- Pass 3: y += qP @ Hcarry; emit y2 (bf16) ----------------
__global__ __launch_bounds__(256) void y_correct(const float* __restrict__ y_loc,
                                                 const float* __restrict__ qP,
                                                 const float* __restrict__ Hc,
                                                 bf16_t* __restrict__ y2b) {
  __shared__ __align__(16) float Hs[D_ * D_ * 2];   // 8 KB
  const int wg = blockIdx.x;
  const int s  = wg & (NSEG - 1);
  const int bh = wg >> 5;
  const int h  = bh & (H_ - 1);
  const int b  = bh >> 3;
  const int t = threadIdx.x;
  const float4* src = (const float4*)(Hc + (size_t)wg * (D_*D_*2));
  ((float4*)Hs)[t]       = src[t];
  ((float4*)Hs)[t + 256] = src[t + 256];
  __syncthreads();
  const int l  = t >> 3;           // 0..31
  const int eb = (t & 7) * 4;      // 4 e-values per thread
  const int lg = s * LSEG + l;
  const size_t rowc = ((size_t)(b*L_ + lg)*H_ + h) * D_;
  const float* qpr = qP + rowc * 2;
  float4 y0 = *(const float4*)(y_loc + (rowc + eb)*2);
  float4 y1 = *(const float4*)(y_loc + (rowc + eb)*2 + 4);
  float ac_r[4] = {y0.x, y0.z, y1.x, y1.z};
  float ac_i[4] = {y0.y, y0.w, y1.y, y1.w};
  for (int d = 0; d < D_; ++d) {
    float2 p = *(const float2*)(qpr + d*2);
    float4 h0v = *(const float4*)&Hs[(d*D_ + eb)*2];
    float4 h1v = *(const float4*)&Hs[(d*D_ + eb)*2 + 4];
    ac_r[0] += p.x*h0v.x - p.y*h0v.y; ac_i[0] += p.x*h0v.y + p.y*h0v.x;
    ac_r[1] += p.x*h0v.z - p.y*h0v.w; ac_i[1] += p.x*h0v.w + p.y*h0v.z;
    ac_r[2] += p.x*h1v.x - p.y*h1v.y; ac_i[2] += p.x*h1v.y + p.y*h1v.x;
    ac_r[3] += p.x*h1v.z - p.y*h1v.w; ac_i[3] += p.x*h1v.w + p.y*h1v.z;
  }
  union { bf16_t bv[8]; uint4 q; } pk;
#pragma unroll
  for (int je = 0; je < 4; ++je) {
    pk.bv[2*je]   = (bf16_t)ac_r[je];
    pk.bv[2*je+1] = (bf16_t)ac_i[je];
  }
  *(uint4*)(y2b + (size_t)(b*L_ + lg) * (H_*D_*2) + (h*D_ + eb)*2) = pk.q;
}

// ---------------- launcher ------------------------------------------------
extern "C" void kernel_launch(void* const* d_in, const int* in_sizes, int n_in,
                              void* d_out, int out_size, void* d_ws, size_t ws_size,
                              hipStream_t stream) {
  const float* x      = (const float*)d_in[0];
  const float* W_in   = (const float*)d_in[1];
  const float* b_in   = (const float*)d_in[2];
  const float* W_qkva = (const float*)d_in[3];
  const float* b_qkva = (const float*)d_in[4];
  const float* W_y    = (const float*)d_in[5];
  const float* b_y    = (const float*)d_in[6];
  const float* W_out  = (const float*)d_in[7];
  const float* b_out  = (const float*)d_in[8];
  const float* h0re   = (const float*)d_in[9];
  const float* h0im   = (const float*)d_in[10];

  char* w = (char*)d_ws;
  const size_t MB = 1ull << 20;
  bf16_t* Wb_in   = (bf16_t*)(w + 0*MB);    // 2 MB
  bf16_t* Wb_qkva = (bf16_t*)(w + 2*MB);    // 4 MB
  bf16_t* Wb_y    = (bf16_t*)(w + 6*MB);    // 1 MB
  bf16_t* Wb_out  = (bf16_t*)(w + 7*MB);    // 2 MB
  bf16_t* xb      = (bf16_t*)(w + 9*MB);    // 8 MB (dead after GEMM1)
  float*  qP      = (float*) (w + 9*MB);    // 8 MB (overlay xb)
  bf16_t* u       = (bf16_t*)(w + 17*MB);   // 8 MB (dead after GEMM2)
  float*  y_loc   = (float*) (w + 17*MB);   // 8 MB (overlay u)
  float*  qkva    = (float*) (w + 25*MB);   // 32 MB (dead after scan)
  float*  Hc      = (float*) (w + 25*MB);   // 8 MB (overlay qkva)
  bf16_t* y2b     = (bf16_t*)(w + 41*MB);   // 4 MB (overlay qkva)
  bf16_t* z       = (bf16_t*)(w + 45*MB);   // 8 MB (overlay qkva)
  float*  Aseg    = (float*) (w + 57*MB);   // 0.25 MB
  float*  Hfin    = (float*) (w + 58*MB);   // 8 MB -> total 66 MB

  cvt_bf16<<<4096, 256, 0, stream>>>(x,      xb,      1048576);
  cvt_bf16<<<1024, 256, 0, stream>>>(W_in,   Wb_in,   262144);
  cvt_bf16<<<2048, 256, 0, stream>>>(W_qkva, Wb_qkva, 524288);
  cvt_bf16<<<512,  256, 0, stream>>>(W_y,    Wb_y,    131072);
  cvt_bf16<<<1024, 256, 0, stream>>>(W_out,  Wb_out,  262144);

  // u = silu(x @ W_in^T + b_in)
  gemm_nt<64,1,1><<<dim3(64, 8), 256, 0, stream>>>(xb, Wb_in, b_in, u, 4096, 1024, 1024);
  // qkva = u @ W_qkva^T + b_qkva  (f32 out)
  gemm_nt<128,0,0><<<dim3(32, 16), 256, 0, stream>>>(u, Wb_qkva, b_qkva, qkva, 4096, 2048, 1024);
  // recurrence
  scan_seg   <<<B_*H_*NSEG, 256, 0, stream>>>(qkva, y_loc, qP, Aseg, Hfin);
  seg_combine<<<B_*H_,      256, 0, stream>>>(h0re, h0im, Aseg, Hfin, Hc);
  y_correct  <<<B_*H_*NSEG, 256, 0, stream>>>(y_loc, qP, Hc, y2b);
  // z = silu(y2 @ W_y^T + b_y)
  gemm_nt<64,1,1><<<dim3(64, 8), 256, 0, stream>>>(y2b, Wb_y, b_y, z, 4096, 1024, 512);
  // out = z @ W_out^T + b_out  (f32)
  gemm_nt<64,0,0><<<dim3(64, 8), 256, 0, stream>>>(z, Wb_out, b_out, (float*)d_out, 4096, 1024, 1024);
}